// Round 23
// baseline (237.200 us; speedup 1.0000x reference)
//
#include <hip/hip_runtime.h>
#include <cstdint>

typedef unsigned short u16;
typedef unsigned int u32;
typedef __attribute__((ext_vector_type(8))) short bf16x8;
typedef __attribute__((ext_vector_type(8))) unsigned short u16x8;
typedef __attribute__((ext_vector_type(4))) float f32x4;
typedef __attribute__((ext_vector_type(2))) float f32x2;

#define DD 256

#if defined(__has_builtin)
#if __has_builtin(__builtin_amdgcn_cvt_pk_fp8_f32) && __has_builtin(__builtin_amdgcn_cvt_pk_f32_fp8)
#define HW_FP8 1
#endif
#if __has_builtin(__builtin_amdgcn_cvt_scalef32_pk_fp4_f32) && __has_builtin(__builtin_amdgcn_cvt_scalef32_pk_f32_fp4)
#define HW_FP4 1
#endif
#endif

// global_load_lds: aux bit1 = NT (gfx94x+ CPol). NT for read-once panels.
#define GLL(g, l) __builtin_amdgcn_global_load_lds( \
        (const __attribute__((address_space(1))) void*)(g), \
        (__attribute__((address_space(3))) void*)(l), 16, 0, 0)
#define GLLNT(g, l) __builtin_amdgcn_global_load_lds( \
        (const __attribute__((address_space(1))) void*)(g), \
        (__attribute__((address_space(3))) void*)(l), 16, 0, 2)

__device__ __forceinline__ u16 f2bf(float f) {
    u32 u = __float_as_uint(f);
    u32 r = (u + 0x7FFFu + ((u >> 16) & 1u)) >> 16;
    return (u16)r;
}
__device__ __forceinline__ float bf2f(u16 v) {
    return __uint_as_float(((u32)v) << 16);
}

// ---- e4m3fn software encode (RNE) / decode (fallback only) ----------------
__device__ __forceinline__ u32 f2e4m3_sw(float f) {
    u32 u = __float_as_uint(f);
    u32 s = u >> 31;
    u32 au = u & 0x7FFFFFFFu;
    float af = __uint_as_float(au);
    u32 b;
    if (af >= 0.015625f) {
        u32 r = au + 0x7FFFFu + ((au >> 20) & 1u);
        u32 E = (r >> 23) - 120u;
        u32 m = (r >> 20) & 7u;
        b = (E << 3) | m;
        if (b > 0x7Eu) b = 0x7Eu;
    } else {
        u32 n = (u32)__float2int_rn(af * 512.0f);
        b = (n > 7u) ? 0x08u : n;
    }
    return b | (s << 7);
}
__device__ __forceinline__ float e4m3f_sw(u32 b) {
    u32 s = (b >> 7) & 1u, E = (b >> 3) & 0xFu, m = b & 7u;
    float vn = __uint_as_float(((E + 120u) << 23) | (m << 20) | (s << 31));
    float vs = __uint_as_float((s << 31) | 0x3B000000u) * (float)m;
    return E ? vn : vs;
}

__device__ __forceinline__ u32 pack4_fp8(f32x4 v) {
#ifdef HW_FP8
    u32 q = __builtin_amdgcn_cvt_pk_fp8_f32(v.x, v.y, 0, 0);
    q = __builtin_amdgcn_cvt_pk_fp8_f32(v.z, v.w, q, 1);
    return q;
#else
    return f2e4m3_sw(v.x) | (f2e4m3_sw(v.y) << 8) |
           (f2e4m3_sw(v.z) << 16) | (f2e4m3_sw(v.w) << 24);
#endif
}

// ---------------------------------------------------------------------------
// fp32 64x64-tile GEMM core (K=256) — tiny weight-fusion GEMMs only
// ---------------------------------------------------------------------------
__device__ __forceinline__ void gemm64_f32(const float* __restrict__ A,
                                           const float* __restrict__ W,
                                           float* __restrict__ C, int bm, int bn) {
    __shared__ float As[16][68];
    __shared__ float Bs[16][68];
    const int tid = threadIdx.x;
    const int tx = tid & 15, ty = tid >> 4;
    const int lm = tid >> 2, lk4 = (tid & 3) * 4;
    const int wk = tid >> 4, wn = (tid & 15) * 4;
    float acc[4][4] = {};
    for (int k0 = 0; k0 < DD; k0 += 16) {
        float4 av = *(const float4*)&A[(size_t)(bm + lm) * DD + k0 + lk4];
        float4 wv = *(const float4*)&W[(size_t)(k0 + wk) * DD + bn + wn];
        __syncthreads();
        As[lk4 + 0][lm] = av.x; As[lk4 + 1][lm] = av.y;
        As[lk4 + 2][lm] = av.z; As[lk4 + 3][lm] = av.w;
        *(float4*)&Bs[wk][wn] = wv;
        __syncthreads();
#pragma unroll
        for (int k = 0; k < 16; ++k) {
            float4 a = *(const float4*)&As[k][ty * 4];
            float4 b = *(const float4*)&Bs[k][tx * 4];
            float ar[4] = {a.x, a.y, a.z, a.w};
            float br[4] = {b.x, b.y, b.z, b.w};
#pragma unroll
            for (int i = 0; i < 4; ++i)
#pragma unroll
                for (int j = 0; j < 4; ++j)
                    acc[i][j] = fmaf(ar[i], br[j], acc[i][j]);
        }
    }
#pragma unroll
    for (int i = 0; i < 4; ++i) {
        float4 o = {acc[i][0], acc[i][1], acc[i][2], acc[i][3]};
        *(float4*)&C[(size_t)(bm + ty * 4 + i) * DD + bn + tx * 4] = o;
    }
}

// prep pass 1 — all INPUT-only products + the 7 fused biases.
__global__ __launch_bounds__(256) void prep1(
    const float* __restrict__ W0, const float* __restrict__ W1a,
    const float* __restrict__ W1b, const float* __restrict__ W2a,
    const float* __restrict__ W2b, const float* __restrict__ Wout,
    const float* __restrict__ b0, const float* __restrict__ b1a,
    const float* __restrict__ b1b, const float* __restrict__ b2a,
    const float* __restrict__ b2b, const float* __restrict__ bout,
    float* __restrict__ FW, float* __restrict__ BF) {
    int z = blockIdx.z;
    if (z < 7) {
        const float *P, *Q;
        int slot = z;
        switch (z) {
            case 0: P = W0;  Q = Wout; break;
            case 1: P = W0;  Q = W1a;  break;
            case 2: P = W1b; Q = Wout; break;
            case 3: P = W0;  Q = W2a;  break;
            case 4: P = W2b; Q = Wout; break;
            case 5: P = Wout; Q = W1a + 65536; slot = 7; break;
            default: P = Wout; Q = W2a + 65536; slot = 8; break;
        }
        gemm64_f32(P, Q, FW + (size_t)slot * 65536, blockIdx.x * 64, blockIdx.y * 64);
        return;
    }
    if (blockIdx.x != 0 || blockIdx.y != 0) return;
    int j = threadIdx.x;
    const float* bz[5] = {b0, b0, b1b, b0, b2b};
    const float* Rz[5] = {Wout, W1a, Wout, W2a, Wout};
    const float* az[5] = {bout, b1a, bout, b2a, bout};
    for (int q = 0; q < 5; ++q) {
        float s = az[q][j];
        for (int k = 0; k < DD; ++k) s += bz[q][k] * Rz[q][k * DD + j];
        BF[q * DD + j] = s;
    }
    __syncthreads();
    {   // e1
        float s = BF[1 * DD + j];
        for (int k = 0; k < DD; ++k) s += BF[k] * W1a[65536 + k * DD + j];
        BF[5 * DD + j] = s;
    }
    {   // e2
        float s = BF[3 * DD + j];
        for (int k = 0; k < DD; ++k) s += BF[2 * DD + k] * W2a[65536 + k * DD + j];
        BF[6 * DD + j] = s;
    }
}

// prep pass 2: P1 = W0@S1 -> slot 5, P2 = W1b@S2 -> slot 6
__global__ __launch_bounds__(256) void prep2(
    const float* __restrict__ W0, const float* __restrict__ W1b,
    float* __restrict__ FW) {
    const float* P = blockIdx.z ? W1b : W0;
    const float* Q = FW + (size_t)(blockIdx.z ? 8 : 7) * 65536;
    gemm64_f32(P, Q, FW + (size_t)(5 + blockIdx.z) * 65536,
               blockIdx.x * 64, blockIdx.y * 64);
}

// prep pass 3: transpose FW slots 0..6 -> bf16 [n][k]  (1792 blocks)
__global__ __launch_bounds__(256) void prep3t(
    const float* __restrict__ FW, u16* __restrict__ WT) {
    int z = blockIdx.x >> 8;
    int t = (blockIdx.x & 255) * 256 + threadIdx.x;
    int i = t >> 8, j = t & 255;
    WT[(size_t)z * 65536 + (size_t)j * DD + i] =
        f2bf(FW[(size_t)z * 65536 + (size_t)i * DD + j]);
}

// ---------------------------------------------------------------------------
// masked-mean gathers — half-wave-per-cell: 256 threads = 4 waves = 8 cells.
// idx/mask are read-once streams -> NONTEMPORAL loads (keep fp4 table in L2).
// ---------------------------------------------------------------------------
template<int K>
__device__ __forceinline__ void gather_body_q(
    const void* __restrict__ srcv, const int* __restrict__ idx,
    const float* __restrict__ mask, u16* __restrict__ out, int C, int gb) {
    int c = gb * 8 + (threadIdx.x >> 5);
    if (c >= C) return;
    int t = threadIdx.x & 31;   // 8-value column group
    constexpr int CH = (K < 16) ? K : 16;
    float acc[8] = {};
    float cnt = 0.f;
#pragma unroll
    for (int k0 = 0; k0 < K; k0 += CH) {
        int ids[CH];
        float ms[CH];
#pragma unroll
        for (int k = 0; k < CH; ++k) {
            ids[k] = __builtin_nontemporal_load(&idx[(size_t)c * K + k0 + k]);
            ms[k] = __builtin_nontemporal_load(&mask[(size_t)c * K + k0 + k]);
        }
#ifdef HW_FP4
        u32 v[CH];
        const u32* __restrict__ src32 = (const u32*)srcv;
#pragma unroll
        for (int k = 0; k < CH; ++k)
            v[k] = src32[(size_t)ids[k] * 32 + t];   // 4B = 8 fp4 values
#pragma unroll
        for (int k = 0; k < CH; ++k) {
            float m = ms[k];
            cnt += m;
            // sel operand must be a LITERAL constant -> hand-unrolled
            f32x2 p0 = __builtin_amdgcn_cvt_scalef32_pk_f32_fp4(v[k], 1.0f, 0);
            f32x2 p1 = __builtin_amdgcn_cvt_scalef32_pk_f32_fp4(v[k], 1.0f, 1);
            f32x2 p2 = __builtin_amdgcn_cvt_scalef32_pk_f32_fp4(v[k], 1.0f, 2);
            f32x2 p3 = __builtin_amdgcn_cvt_scalef32_pk_f32_fp4(v[k], 1.0f, 3);
            acc[0] = fmaf(m, p0.x, acc[0]); acc[1] = fmaf(m, p0.y, acc[1]);
            acc[2] = fmaf(m, p1.x, acc[2]); acc[3] = fmaf(m, p1.y, acc[3]);
            acc[4] = fmaf(m, p2.x, acc[4]); acc[5] = fmaf(m, p2.y, acc[5]);
            acc[6] = fmaf(m, p3.x, acc[6]); acc[7] = fmaf(m, p3.y, acc[7]);
        }
#else
        uint2 v[CH];
        const u32* __restrict__ src32 = (const u32*)srcv;
#pragma unroll
        for (int k = 0; k < CH; ++k)
            v[k] = *(const uint2*)&src32[(size_t)ids[k] * 64 + t * 2];  // 8 fp8
#pragma unroll
        for (int k = 0; k < CH; ++k) {
            float m = ms[k];
            cnt += m;
#ifdef HW_FP8
            f32x2 p0 = __builtin_amdgcn_cvt_pk_f32_fp8(v[k].x, 0);
            f32x2 p1 = __builtin_amdgcn_cvt_pk_f32_fp8(v[k].x, 1);
            f32x2 p2 = __builtin_amdgcn_cvt_pk_f32_fp8(v[k].y, 0);
            f32x2 p3 = __builtin_amdgcn_cvt_pk_f32_fp8(v[k].y, 1);
            acc[0] = fmaf(m, p0.x, acc[0]); acc[1] = fmaf(m, p0.y, acc[1]);
            acc[2] = fmaf(m, p1.x, acc[2]); acc[3] = fmaf(m, p1.y, acc[3]);
            acc[4] = fmaf(m, p2.x, acc[4]); acc[5] = fmaf(m, p2.y, acc[5]);
            acc[6] = fmaf(m, p3.x, acc[6]); acc[7] = fmaf(m, p3.y, acc[7]);
#else
#pragma unroll
            for (int q = 0; q < 4; ++q) {
                acc[q]     = fmaf(m, e4m3f_sw((v[k].x >> (8 * q)) & 0xFFu), acc[q]);
                acc[q + 4] = fmaf(m, e4m3f_sw((v[k].y >> (8 * q)) & 0xFFu), acc[q + 4]);
            }
#endif
        }
#endif
    }
    float inv = (cnt > 0.f) ? 1.f / fmaxf(cnt, 1.f) : 0.f;
    u16x8 o;
#pragma unroll
    for (int q = 0; q < 8; ++q) o[q] = f2bf(acc[q] * inv);
    *(u16x8*)&out[(size_t)c * DD + t * 8] = o;
}

// all three X-sourced gathers; HEAVY K=32 blocks dispatched FIRST (tail fix)
__global__ __launch_bounds__(256) void gather3(
    const void* __restrict__ Xq,
    const int* __restrict__ i1, const float* __restrict__ m1, u16* __restrict__ A1b,
    const int* __restrict__ i2, const float* __restrict__ m2, u16* __restrict__ G1b,
    int C1,
    const int* __restrict__ i3, const float* __restrict__ m3, u16* __restrict__ A2b,
    int C2) {
    int b = blockIdx.x;
    int nA2 = (C2 + 7) / 8;
    int n1 = (C1 + 7) / 8;
    if (b < nA2)           gather_body_q<32>(Xq, i3, m3, A2b, C2, b);
    else if (b < nA2 + n1) gather_body_q<16>(Xq, i1, m1, A1b, C1, b - nA2);
    else                   gather_body_q<16>(Xq, i2, m2, G1b, C1, b - nA2 - n1);
}

// ---------------------------------------------------------------------------
// WIDE MFMA bf16 GEMM body, BK=64: 512 threads, 8 waves (2x4), 128x256 tile.
// LDS [row][64] bf16; 16B-slot swizzle: slot' = slot ^ (row & 7).
// fp32 final outputs: NONTEMPORAL stores. ANT=1: A-panels are read-once ->
// NT global_load_lds (aux bit1). B weight panels always cached.
// ---------------------------------------------------------------------------
template<int TWO, int RELU_BF, int WF32, int WBF16, int ANT>
__device__ __forceinline__ void gemm_wide_body(
    const u16* __restrict__ A0, const u16* __restrict__ A1p,
    const u16* __restrict__ B0t, const u16* __restrict__ B1t,
    const float* __restrict__ bias, float* __restrict__ Cf,
    u16* __restrict__ Cb, int M, int bx) {
    __shared__ __align__(16) u16 As[8192];    // [128][64] swizzled (16KB)
    __shared__ __align__(16) u16 Bs[16384];   // [256][64] swizzled (32KB)
    const int tid = threadIdx.x;
    const int wave = tid >> 6;
    const int lane = tid & 63;
    const int bm = bx * 128;
    const int wr = wave >> 2, wc = wave & 3;

    size_t aoff[2];
#pragma unroll
    for (int r = 0; r < 2; ++r) {
        int p = r * 512 + tid;
        int row = p >> 3;
        int s = (p & 7) ^ (row & 7);
        aoff[r] = (size_t)min(bm + row, M - 1) * DD + s * 8;
    }
    size_t boff[4];
#pragma unroll
    for (int r = 0; r < 4; ++r) {
        int p = r * 512 + tid;
        int row = p >> 3;
        int s = (p & 7) ^ (row & 7);
        boff[r] = (size_t)row * DD + s * 8;
    }

    f32x4 acc[4][4] = {};
    const int ra = wr * 64 + (lane & 15);
    const int rb = wc * 64 + (lane & 15);
    const int sF = lane >> 4;

    const int nparts = TWO ? 2 : 1;
    for (int part = 0; part < nparts; ++part) {
        const u16* __restrict__ A  = part ? A1p : A0;
        const u16* __restrict__ Bt = part ? B1t : B0t;
        for (int k0 = 0; k0 < DD; k0 += 64) {
            __syncthreads();
#pragma unroll
            for (int r = 0; r < 2; ++r) {
                if (ANT) GLLNT(A + aoff[r] + k0, As + r * 4096 + wave * 512);
                else     GLL(A + aoff[r] + k0, As + r * 4096 + wave * 512);
            }
#pragma unroll
            for (int r = 0; r < 4; ++r)
                GLL(Bt + boff[r] + k0, Bs + r * 4096 + wave * 512);
            __syncthreads();

#pragma unroll
            for (int ks = 0; ks < 2; ++ks) {
                bf16x8 af[4], bfr[4];
#pragma unroll
                for (int mi = 0; mi < 4; ++mi) {
                    int row = ra + mi * 16;
                    int sl = (ks * 4 + sF) ^ (row & 7);
                    af[mi] = *(const bf16x8*)(As + row * 64 + sl * 8);
                }
#pragma unroll
                for (int ni = 0; ni < 4; ++ni) {
                    int row = rb + ni * 16;
                    int sl = (ks * 4 + sF) ^ (row & 7);
                    bfr[ni] = *(const bf16x8*)(Bs + row * 64 + sl * 8);
                }
#pragma unroll
                for (int mi = 0; mi < 4; ++mi)
#pragma unroll
                    for (int ni = 0; ni < 4; ++ni)
                        acc[mi][ni] = __builtin_amdgcn_mfma_f32_16x16x32_bf16(
                            af[mi], bfr[ni], acc[mi][ni], 0, 0, 0);
            }
        }
    }

    const int col_l = wc * 64 + (lane & 15);
    const int rbase = bm + wr * 64 + (lane >> 4) * 4;
#pragma unroll
    for (int mi = 0; mi < 4; ++mi) {
#pragma unroll
        for (int r = 0; r < 4; ++r) {
            int row = rbase + mi * 16 + r;
            if (row < M) {
#pragma unroll
                for (int ni = 0; ni < 4; ++ni) {
                    int col = col_l + ni * 16;
                    float v = acc[mi][ni][r] + bias[col];
                    if (WF32)
                        __builtin_nontemporal_store(v, &Cf[(size_t)row * DD + col]);
                    if (WBF16) {
                        float vb = RELU_BF ? fmaxf(v, 0.f) : v;
                        Cb[(size_t)row * DD + col] = f2bf(vb);
                    }
                }
            }
        }
    }
}

template<int TWO, int RELU_BF, int WF32, int WBF16, int ANT>
__global__ __launch_bounds__(512) void gemm_wide(
    const u16* __restrict__ A0, const u16* __restrict__ A1p,
    const u16* __restrict__ B0t, const u16* __restrict__ B1t,
    const float* __restrict__ bias, float* __restrict__ Cf,
    u16* __restrict__ Cb, int M) {
    gemm_wide_body<TWO, RELU_BF, WF32, WBF16, ANT>(A0, A1p, B0t, B1t, bias,
                                                   Cf, Cb, M, blockIdx.x);
}

// ---------------------------------------------------------------------------
// emb0_fused (BK=64): A reg-staged from fp32 X (NT loads — read once, via
// clang ext-vector f32x4: __builtin_nontemporal_load requires it);
// Xq side-product during MFMA phase; emb0 stores nontemporal.
// ---------------------------------------------------------------------------
__global__ __launch_bounds__(512) void emb0_fused(
    const float* __restrict__ X, const u16* __restrict__ Bt,
    const float* __restrict__ bias, float* __restrict__ Cf,
    u32* __restrict__ Xq, int M) {
    __shared__ __align__(16) u16 As[8192];
    __shared__ __align__(16) u16 Bs[16384];
    const int tid = threadIdx.x;
    const int wave = tid >> 6;
    const int lane = tid & 63;
    const int bm = blockIdx.x * 128;
    const int wr = wave >> 2, wc = wave & 3;

    int rowL[2], colS[2];
    bool wq[2];
#pragma unroll
    for (int r = 0; r < 2; ++r) {
        int p = r * 512 + tid;
        int row = p >> 3;
        int s = (p & 7) ^ (row & 7);
        rowL[r] = min(bm + row, M - 1);
        colS[r] = s * 8;
        wq[r] = (bm + row) < M;
    }
    size_t boff[4];
#pragma unroll
    for (int r = 0; r < 4; ++r) {
        int p = r * 512 + tid;
        int row = p >> 3;
        int s = (p & 7) ^ (row & 7);
        boff[r] = (size_t)row * DD + s * 8;
    }

    f32x4 acc[4][4] = {};
    const int ra = wr * 64 + (lane & 15);
    const int rb = wc * 64 + (lane & 15);
    const int sF = lane >> 4;

    for (int k0 = 0; k0 < DD; k0 += 64) {
        f32x4 x0[2], x1[2];
#pragma unroll
        for (int r = 0; r < 2; ++r) {
            const float* xs = X + (size_t)rowL[r] * DD + k0 + colS[r];
            x0[r] = __builtin_nontemporal_load((const f32x4*)xs);
            x1[r] = __builtin_nontemporal_load((const f32x4*)(xs + 4));
        }
        __syncthreads();   // previous iteration's LDS reads done
#pragma unroll
        for (int r = 0; r < 4; ++r)
            GLL(Bt + boff[r] + k0, Bs + r * 4096 + wave * 512);
#pragma unroll
        for (int r = 0; r < 2; ++r) {
            bf16x8 av;
            av[0] = (short)f2bf(x0[r].x); av[1] = (short)f2bf(x0[r].y);
            av[2] = (short)f2bf(x0[r].z); av[3] = (short)f2bf(x0[r].w);
            av[4] = (short)f2bf(x1[r].x); av[5] = (short)f2bf(x1[r].y);
            av[6] = (short)f2bf(x1[r].z); av[7] = (short)f2bf(x1[r].w);
            *(bf16x8*)(As + (size_t)(r * 512 + tid) * 8) = av;
        }
        __syncthreads();   // drains GLL (vmcnt) + ds_write (lgkm)

        // Xq side-product during MFMA phase (drains at next iter's barrier)
#pragma unroll
        for (int r = 0; r < 2; ++r) {
            if (wq[r]) {
#ifdef HW_FP4
                u32 q = 0;
                q = __builtin_amdgcn_cvt_scalef32_pk_fp4_f32(q, x0[r].x, x0[r].y, 1.0f, 0);
                q = __builtin_amdgcn_cvt_scalef32_pk_fp4_f32(q, x0[r].z, x0[r].w, 1.0f, 1);
                q = __builtin_amdgcn_cvt_scalef32_pk_fp4_f32(q, x1[r].x, x1[r].y, 1.0f, 2);
                q = __builtin_amdgcn_cvt_scalef32_pk_fp4_f32(q, x1[r].z, x1[r].w, 1.0f, 3);
                Xq[(size_t)rowL[r] * 32 + ((k0 + colS[r]) >> 3)] = q;
#else
                uint2 qq = {pack4_fp8(x0[r]), pack4_fp8(x1[r])};
                *(uint2*)&Xq[(size_t)rowL[r] * 64 + ((k0 + colS[r]) >> 2)] = qq;
#endif
            }
        }

#pragma unroll
        for (int ks = 0; ks < 2; ++ks) {
            bf16x8 af[4], bfr[4];
#pragma unroll
            for (int mi = 0; mi < 4; ++mi) {
                int row = ra + mi * 16;
                int sl = (ks * 4 + sF) ^ (row & 7);
                af[mi] = *(const bf16x8*)(As + row * 64 + sl * 8);
            }
#pragma unroll
            for (int ni = 0; ni < 4; ++ni) {
                int row = rb + ni * 16;
                int sl = (ks * 4 + sF) ^ (row & 7);
                bfr[ni] = *(const bf16x8*)(Bs + row * 64 + sl * 8);
            }
#pragma unroll
            for (int mi = 0; mi < 4; ++mi)
#pragma unroll
                for (int ni = 0; ni < 4; ++ni)
                    acc[mi][ni] = __builtin_amdgcn_mfma_f32_16x16x32_bf16(
                        af[mi], bfr[ni], acc[mi][ni], 0, 0, 0);
        }
    }

    const int col_l = wc * 64 + (lane & 15);
    const int rbase = bm + wr * 64 + (lane >> 4) * 4;
#pragma unroll
    for (int mi = 0; mi < 4; ++mi)
#pragma unroll
        for (int r = 0; r < 4; ++r) {
            int row = rbase + mi * 16 + r;
            if (row < M) {
#pragma unroll
                for (int ni = 0; ni < 4; ++ni) {
                    int col = col_l + ni * 16;
                    __builtin_nontemporal_store(acc[mi][ni][r] + bias[col],
                                                &Cf[(size_t)row * DD + col]);
                }
            }
        }
}

// ---------------------------------------------------------------------------
// emb1 (wide GEMM, cached A: H1b also gathered by g2) + G2 gather, ONE launch.
// ---------------------------------------------------------------------------
__global__ __launch_bounds__(512) void emb1_g2(
    const u16* __restrict__ H1b, const u16* __restrict__ V1t,
    const float* __restrict__ d1c, float* __restrict__ emb1, int C1, int nA,
    const int* __restrict__ d2_bi, const float* __restrict__ d2_bm,
    u16* __restrict__ G2b, int C2) {
    int b = blockIdx.x;
    if (b < nA) {
        gemm_wide_body<0, 0, 1, 0, 0>(H1b, nullptr, V1t, nullptr, d1c, emb1,
                                      nullptr, C1, b);
        return;
    }
    int c = (b - nA) * 8 + (threadIdx.x >> 6);
    if (c >= C2) return;
    int t = threadIdx.x & 63;
    constexpr int K = 8;
    int ids[K];
    float ms[K];
    ushort4 v[K];
#pragma unroll
    for (int k = 0; k < K; ++k) {
        ids[k] = __builtin_nontemporal_load(&d2_bi[(size_t)c * K + k]);
        ms[k] = __builtin_nontemporal_load(&d2_bm[(size_t)c * K + k]);
    }
#pragma unroll
    for (int k = 0; k < K; ++k)
        v[k] = *(const ushort4*)&H1b[(size_t)ids[k] * DD + t * 4];
    float a0 = 0, a1 = 0, a2 = 0, a3 = 0, cnt = 0;
#pragma unroll
    for (int k = 0; k < K; ++k) {
        float m = ms[k];
        cnt += m;
        a0 += m * bf2f(v[k].x); a1 += m * bf2f(v[k].y);
        a2 += m * bf2f(v[k].z); a3 += m * bf2f(v[k].w);
    }
    float inv = (cnt > 0.f) ? 1.f / fmaxf(cnt, 1.f) : 0.f;
    ushort4 o = {f2bf(a0 * inv), f2bf(a1 * inv), f2bf(a2 * inv), f2bf(a3 * inv)};
    *(ushort4*)&G2b[(size_t)c * DD + t * 4] = o;
}

extern "C" void kernel_launch(void* const* d_in, const int* in_sizes, int n_in,
                              void* d_out, int out_size, void* d_ws, size_t ws_size,
                              hipStream_t stream) {
    const float* X     = (const float*)d_in[0];
    const int*   d1_ci = (const int*)d_in[1];
    const int*   d1_bi = (const int*)d_in[2];
    const int*   d2_ci = (const int*)d_in[3];
    const int*   d2_bi = (const int*)d_in[4];
    const float* d1_cm = (const float*)d_in[5];
    const float* d1_bm = (const float*)d_in[6];
    const float* d2_cm = (const float*)d_in[7];
    const float* d2_bm = (const float*)d_in[8];
    const float* W0   = (const float*)d_in[9];
    const float* b0   = (const float*)d_in[10];
    const float* W1a  = (const float*)d_in[11];
    const float* b1a  = (const float*)d_in[12];
    const float* W1b  = (const float*)d_in[13];
    const float* b1b  = (const float*)d_in[14];
    const float* W2a  = (const float*)d_in[15];
    const float* b2a  = (const float*)d_in[16];
    const float* W2b  = (const float*)d_in[17];
    const float* b2b  = (const float*)d_in[18];
    const float* Wout = (const float*)d_in[19];
    const float* bout = (const float*)d_in[20];

    const int N  = in_sizes[0] / DD;   // 100000
    const int C1 = in_sizes[1] / 16;   // 50000
    const int C2 = in_sizes[3] / 32;   // 10000

    float* out  = (float*)d_out;
    float* emb0 = out;
    float* emb1 = out + (size_t)N * DD;
    float* emb2 = out + (size_t)(N + C1) * DD;

    // ---- workspace layout (~122 MB of ~655 MB) ----
    u16* A1b = (u16*)d_ws;                     // [C1,256]
    u16* G1b = A1b + (size_t)C1 * DD;          // [C1,256]
    u16* H1b = G1b + (size_t)C1 * DD;          // [C1,256] relu(h1) bf16
    u16* WT  = H1b + (size_t)C1 * DD;          // 7 x 256x256 bf16 transposed
    float* FW = (float*)(((uintptr_t)(WT + 7 * 65536) + 15) & ~(uintptr_t)15);  // 9 slots
    float* BF = FW + 9 * 65536;                // 7 x 256 fused biases
    u16* A2b = (u16*)(((uintptr_t)(BF + 7 * 256) + 15) & ~(uintptr_t)15);
    u16* G2b = A2b + (size_t)C2 * DD;
    u16* H2b = G2b + (size_t)C2 * DD;
    u32* Xq  = (u32*)(((uintptr_t)(H2b + (size_t)C2 * DD) + 15) & ~(uintptr_t)15);  // fp4/fp8 table

    u16* Wf_t = WT + 0 * 65536;
    u16* U1_t = WT + 1 * 65536;
    u16* V1_t = WT + 2 * 65536;
    u16* U2_t = WT + 3 * 65536;
    u16* V2_t = WT + 4 * 65536;
    u16* P1_t = WT + 5 * 65536;
    u16* P2_t = WT + 6 * 65536;

    dim3 tb(256);
    dim3 tw(512);

    // 1) input-only weight products + biases
    prep1<<<dim3(4, 4, 8), tb, 0, stream>>>(W0, W1a, W1b, W2a, W2b, Wout,
                                            b0, b1a, b1b, b2a, b2b, bout, FW, BF);
    // 2) second-level products P1, P2
    prep2<<<dim3(4, 4, 2), tb, 0, stream>>>(W0, W1b, FW);
    // 3) transpose fused weights -> bf16 [n][k]
    prep3t<<<1792, tb, 0, stream>>>(FW, WT);

    // 4) fused emb0 GEMM (reads fp32 X once, emits emb0 + quantized Xq)
    emb0_fused<<<(N + 127) / 128, tw, 0, stream>>>(
        X, Wf_t, BF + 0, emb0, Xq, N);

    // 5) all X gathers from the quantized table — heavy A2 blocks first,
    //    8 cells per block (half-wave per cell)
    const int n1g = (C1 + 7) / 8;    // 6250
    const int nA2g = (C2 + 7) / 8;   // 1250
    gather3<<<nA2g + 2 * n1g, tb, 0, stream>>>(
        Xq, d1_ci, d1_cm, A1b, d1_bi, d1_bm, G1b, C1, d2_ci, d2_cm, A2b, C2);

    // 6) h1 GEMM (wide, A panels read-once -> NT): H1b = relu(...) as bf16
    gemm_wide<1, 1, 0, 1, 1><<<(C1 + 127) / 128, tw, 0, stream>>>(
        A1b, G1b, U1_t, P1_t, BF + 5 * 256, nullptr, H1b, C1);

    // 7) emb1 = H1b@V1 + d1c  AND  G2 gather from H1b  (one launch)
    const int nEmb1 = (C1 + 127) / 128;   // 391
    const int nG2   = (C2 + 7) / 8;       // 1250
    emb1_g2<<<nEmb1 + nG2, tw, 0, stream>>>(
        H1b, V1_t, BF + 2 * 256, emb1, C1, nEmb1,
        d2_bi, d2_bm, G2b, C2);

    // 8) h2 GEMM (wide, A panels read-once -> NT)
    gemm_wide<1, 1, 0, 1, 1><<<(C2 + 127) / 128, tw, 0, stream>>>(
        A2b, G2b, U2_t, P2_t, BF + 6 * 256, nullptr, H2b, C2);

    // 9) emb2 GEMM (wide, A panel read-once -> NT)
    gemm_wide<0, 0, 1, 0, 1><<<(C2 + 127) / 128, tw, 0, stream>>>(
        H2b, nullptr, V2_t, nullptr, BF + 4 * 256, emb2, nullptr, C2);
}

// Round 24
// 226.634 us; speedup vs baseline: 1.0466x; 1.0466x over previous
//
#include <hip/hip_runtime.h>
#include <cstdint>

typedef unsigned short u16;
typedef unsigned int u32;
typedef __attribute__((ext_vector_type(8))) short bf16x8;
typedef __attribute__((ext_vector_type(8))) unsigned short u16x8;
typedef __attribute__((ext_vector_type(4))) float f32x4;
typedef __attribute__((ext_vector_type(2))) float f32x2;

#define DD 256

#if defined(__has_builtin)
#if __has_builtin(__builtin_amdgcn_cvt_pk_fp8_f32) && __has_builtin(__builtin_amdgcn_cvt_pk_f32_fp8)
#define HW_FP8 1
#endif
#if __has_builtin(__builtin_amdgcn_cvt_scalef32_pk_fp4_f32) && __has_builtin(__builtin_amdgcn_cvt_scalef32_pk_f32_fp4)
#define HW_FP4 1
#endif
#endif

#define GLL(g, l) __builtin_amdgcn_global_load_lds( \
        (const __attribute__((address_space(1))) void*)(g), \
        (__attribute__((address_space(3))) void*)(l), 16, 0, 0)

__device__ __forceinline__ u16 f2bf(float f) {
    u32 u = __float_as_uint(f);
    u32 r = (u + 0x7FFFu + ((u >> 16) & 1u)) >> 16;
    return (u16)r;
}
__device__ __forceinline__ float bf2f(u16 v) {
    return __uint_as_float(((u32)v) << 16);
}

// ---- e4m3fn software encode (RNE) / decode (fallback only) ----------------
__device__ __forceinline__ u32 f2e4m3_sw(float f) {
    u32 u = __float_as_uint(f);
    u32 s = u >> 31;
    u32 au = u & 0x7FFFFFFFu;
    float af = __uint_as_float(au);
    u32 b;
    if (af >= 0.015625f) {
        u32 r = au + 0x7FFFFu + ((au >> 20) & 1u);
        u32 E = (r >> 23) - 120u;
        u32 m = (r >> 20) & 7u;
        b = (E << 3) | m;
        if (b > 0x7Eu) b = 0x7Eu;
    } else {
        u32 n = (u32)__float2int_rn(af * 512.0f);
        b = (n > 7u) ? 0x08u : n;
    }
    return b | (s << 7);
}
__device__ __forceinline__ float e4m3f_sw(u32 b) {
    u32 s = (b >> 7) & 1u, E = (b >> 3) & 0xFu, m = b & 7u;
    float vn = __uint_as_float(((E + 120u) << 23) | (m << 20) | (s << 31));
    float vs = __uint_as_float((s << 31) | 0x3B000000u) * (float)m;
    return E ? vn : vs;
}

__device__ __forceinline__ u32 pack4_fp8(float4 v) {
#ifdef HW_FP8
    u32 q = __builtin_amdgcn_cvt_pk_fp8_f32(v.x, v.y, 0, 0);
    q = __builtin_amdgcn_cvt_pk_fp8_f32(v.z, v.w, q, 1);
    return q;
#else
    return f2e4m3_sw(v.x) | (f2e4m3_sw(v.y) << 8) |
           (f2e4m3_sw(v.z) << 16) | (f2e4m3_sw(v.w) << 24);
#endif
}

// ---------------------------------------------------------------------------
// fp32 64x64-tile GEMM core (K=256) — tiny weight-fusion GEMMs only
// ---------------------------------------------------------------------------
__device__ __forceinline__ void gemm64_f32(const float* __restrict__ A,
                                           const float* __restrict__ W,
                                           float* __restrict__ C, int bm, int bn) {
    __shared__ float As[16][68];
    __shared__ float Bs[16][68];
    const int tid = threadIdx.x;
    const int tx = tid & 15, ty = tid >> 4;
    const int lm = tid >> 2, lk4 = (tid & 3) * 4;
    const int wk = tid >> 4, wn = (tid & 15) * 4;
    float acc[4][4] = {};
    for (int k0 = 0; k0 < DD; k0 += 16) {
        float4 av = *(const float4*)&A[(size_t)(bm + lm) * DD + k0 + lk4];
        float4 wv = *(const float4*)&W[(size_t)(k0 + wk) * DD + bn + wn];
        __syncthreads();
        As[lk4 + 0][lm] = av.x; As[lk4 + 1][lm] = av.y;
        As[lk4 + 2][lm] = av.z; As[lk4 + 3][lm] = av.w;
        *(float4*)&Bs[wk][wn] = wv;
        __syncthreads();
#pragma unroll
        for (int k = 0; k < 16; ++k) {
            float4 a = *(const float4*)&As[k][ty * 4];
            float4 b = *(const float4*)&Bs[k][tx * 4];
            float ar[4] = {a.x, a.y, a.z, a.w};
            float br[4] = {b.x, b.y, b.z, b.w};
#pragma unroll
            for (int i = 0; i < 4; ++i)
#pragma unroll
                for (int j = 0; j < 4; ++j)
                    acc[i][j] = fmaf(ar[i], br[j], acc[i][j]);
        }
    }
#pragma unroll
    for (int i = 0; i < 4; ++i) {
        float4 o = {acc[i][0], acc[i][1], acc[i][2], acc[i][3]};
        *(float4*)&C[(size_t)(bm + ty * 4 + i) * DD + bn + tx * 4] = o;
    }
}

// prep pass 1 — all INPUT-only products + the 7 fused biases.
__global__ __launch_bounds__(256) void prep1(
    const float* __restrict__ W0, const float* __restrict__ W1a,
    const float* __restrict__ W1b, const float* __restrict__ W2a,
    const float* __restrict__ W2b, const float* __restrict__ Wout,
    const float* __restrict__ b0, const float* __restrict__ b1a,
    const float* __restrict__ b1b, const float* __restrict__ b2a,
    const float* __restrict__ b2b, const float* __restrict__ bout,
    float* __restrict__ FW, float* __restrict__ BF) {
    int z = blockIdx.z;
    if (z < 7) {
        const float *P, *Q;
        int slot = z;
        switch (z) {
            case 0: P = W0;  Q = Wout; break;
            case 1: P = W0;  Q = W1a;  break;
            case 2: P = W1b; Q = Wout; break;
            case 3: P = W0;  Q = W2a;  break;
            case 4: P = W2b; Q = Wout; break;
            case 5: P = Wout; Q = W1a + 65536; slot = 7; break;
            default: P = Wout; Q = W2a + 65536; slot = 8; break;
        }
        gemm64_f32(P, Q, FW + (size_t)slot * 65536, blockIdx.x * 64, blockIdx.y * 64);
        return;
    }
    if (blockIdx.x != 0 || blockIdx.y != 0) return;
    int j = threadIdx.x;
    const float* bz[5] = {b0, b0, b1b, b0, b2b};
    const float* Rz[5] = {Wout, W1a, Wout, W2a, Wout};
    const float* az[5] = {bout, b1a, bout, b2a, bout};
    for (int q = 0; q < 5; ++q) {
        float s = az[q][j];
        for (int k = 0; k < DD; ++k) s += bz[q][k] * Rz[q][k * DD + j];
        BF[q * DD + j] = s;
    }
    __syncthreads();
    {   // e1
        float s = BF[1 * DD + j];
        for (int k = 0; k < DD; ++k) s += BF[k] * W1a[65536 + k * DD + j];
        BF[5 * DD + j] = s;
    }
    {   // e2
        float s = BF[3 * DD + j];
        for (int k = 0; k < DD; ++k) s += BF[2 * DD + k] * W2a[65536 + k * DD + j];
        BF[6 * DD + j] = s;
    }
}

// prep pass 2: P1 = W0@S1 -> slot 5, P2 = W1b@S2 -> slot 6
__global__ __launch_bounds__(256) void prep2(
    const float* __restrict__ W0, const float* __restrict__ W1b,
    float* __restrict__ FW) {
    const float* P = blockIdx.z ? W1b : W0;
    const float* Q = FW + (size_t)(blockIdx.z ? 8 : 7) * 65536;
    gemm64_f32(P, Q, FW + (size_t)(5 + blockIdx.z) * 65536,
               blockIdx.x * 64, blockIdx.y * 64);
}

// prep pass 3: transpose FW slots 0..6 -> bf16 [n][k]  (1792 blocks)
__global__ __launch_bounds__(256) void prep3t(
    const float* __restrict__ FW, u16* __restrict__ WT) {
    int z = blockIdx.x >> 8;
    int t = (blockIdx.x & 255) * 256 + threadIdx.x;
    int i = t >> 8, j = t & 255;
    WT[(size_t)z * 65536 + (size_t)j * DD + i] =
        f2bf(FW[(size_t)z * 65536 + (size_t)i * DD + j]);
}

// ---------------------------------------------------------------------------
// masked-mean gathers — half-wave-per-cell: 256 threads = 4 waves = 8 cells.
// Lane l: cell = base + (l>>5), covers columns (l&31)*8 .. +7 via ONE u32
// (fp4: 8 values) or uint2 (fp8 fallback). One wave-load serves TWO rows.
// ---------------------------------------------------------------------------
template<int K>
__device__ __forceinline__ void gather_body_q(
    const void* __restrict__ srcv, const int* __restrict__ idx,
    const float* __restrict__ mask, u16* __restrict__ out, int C, int gb) {
    int c = gb * 8 + (threadIdx.x >> 5);
    if (c >= C) return;
    int t = threadIdx.x & 31;   // 8-value column group
    constexpr int CH = (K < 16) ? K : 16;
    float acc[8] = {};
    float cnt = 0.f;
#pragma unroll
    for (int k0 = 0; k0 < K; k0 += CH) {
        int ids[CH];
        float ms[CH];
#pragma unroll
        for (int k = 0; k < CH; ++k) {
            ids[k] = idx[(size_t)c * K + k0 + k];
            ms[k] = mask[(size_t)c * K + k0 + k];
        }
#ifdef HW_FP4
        u32 v[CH];
        const u32* __restrict__ src32 = (const u32*)srcv;
#pragma unroll
        for (int k = 0; k < CH; ++k)
            v[k] = src32[(size_t)ids[k] * 32 + t];   // 4B = 8 fp4 values
#pragma unroll
        for (int k = 0; k < CH; ++k) {
            float m = ms[k];
            cnt += m;
            // sel operand must be a LITERAL constant -> hand-unrolled
            f32x2 p0 = __builtin_amdgcn_cvt_scalef32_pk_f32_fp4(v[k], 1.0f, 0);
            f32x2 p1 = __builtin_amdgcn_cvt_scalef32_pk_f32_fp4(v[k], 1.0f, 1);
            f32x2 p2 = __builtin_amdgcn_cvt_scalef32_pk_f32_fp4(v[k], 1.0f, 2);
            f32x2 p3 = __builtin_amdgcn_cvt_scalef32_pk_f32_fp4(v[k], 1.0f, 3);
            acc[0] = fmaf(m, p0.x, acc[0]); acc[1] = fmaf(m, p0.y, acc[1]);
            acc[2] = fmaf(m, p1.x, acc[2]); acc[3] = fmaf(m, p1.y, acc[3]);
            acc[4] = fmaf(m, p2.x, acc[4]); acc[5] = fmaf(m, p2.y, acc[5]);
            acc[6] = fmaf(m, p3.x, acc[6]); acc[7] = fmaf(m, p3.y, acc[7]);
        }
#else
        uint2 v[CH];
        const u32* __restrict__ src32 = (const u32*)srcv;
#pragma unroll
        for (int k = 0; k < CH; ++k)
            v[k] = *(const uint2*)&src32[(size_t)ids[k] * 64 + t * 2];  // 8 fp8
#pragma unroll
        for (int k = 0; k < CH; ++k) {
            float m = ms[k];
            cnt += m;
#ifdef HW_FP8
            f32x2 p0 = __builtin_amdgcn_cvt_pk_f32_fp8(v[k].x, 0);
            f32x2 p1 = __builtin_amdgcn_cvt_pk_f32_fp8(v[k].x, 1);
            f32x2 p2 = __builtin_amdgcn_cvt_pk_f32_fp8(v[k].y, 0);
            f32x2 p3 = __builtin_amdgcn_cvt_pk_f32_fp8(v[k].y, 1);
            acc[0] = fmaf(m, p0.x, acc[0]); acc[1] = fmaf(m, p0.y, acc[1]);
            acc[2] = fmaf(m, p1.x, acc[2]); acc[3] = fmaf(m, p1.y, acc[3]);
            acc[4] = fmaf(m, p2.x, acc[4]); acc[5] = fmaf(m, p2.y, acc[5]);
            acc[6] = fmaf(m, p3.x, acc[6]); acc[7] = fmaf(m, p3.y, acc[7]);
#else
#pragma unroll
            for (int q = 0; q < 4; ++q) {
                acc[q]     = fmaf(m, e4m3f_sw((v[k].x >> (8 * q)) & 0xFFu), acc[q]);
                acc[q + 4] = fmaf(m, e4m3f_sw((v[k].y >> (8 * q)) & 0xFFu), acc[q + 4]);
            }
#endif
        }
#endif
    }
    float inv = (cnt > 0.f) ? 1.f / fmaxf(cnt, 1.f) : 0.f;
    u16x8 o;
#pragma unroll
    for (int q = 0; q < 8; ++q) o[q] = f2bf(acc[q] * inv);
    *(u16x8*)&out[(size_t)c * DD + t * 8] = o;
}

// all three X-sourced gathers; HEAVY K=32 blocks dispatched FIRST (tail fix)
__global__ __launch_bounds__(256) void gather3(
    const void* __restrict__ Xq,
    const int* __restrict__ i1, const float* __restrict__ m1, u16* __restrict__ A1b,
    const int* __restrict__ i2, const float* __restrict__ m2, u16* __restrict__ G1b,
    int C1,
    const int* __restrict__ i3, const float* __restrict__ m3, u16* __restrict__ A2b,
    int C2) {
    int b = blockIdx.x;
    int nA2 = (C2 + 7) / 8;
    int n1 = (C1 + 7) / 8;
    if (b < nA2)           gather_body_q<32>(Xq, i3, m3, A2b, C2, b);
    else if (b < nA2 + n1) gather_body_q<16>(Xq, i1, m1, A1b, C1, b - nA2);
    else                   gather_body_q<16>(Xq, i2, m2, G1b, C1, b - nA2 - n1);
}

// ---------------------------------------------------------------------------
// WIDE MFMA bf16 GEMM body, BK=64: 512 threads, 8 waves (2x4), 128x256 tile.
// LDS [row][64] bf16; 16B-slot swizzle: slot' = slot ^ (row & 7).
// fp32 outputs (emb0/emb1/emb2 = final, never re-read) use NONTEMPORAL
// stores so they don't evict L2 working sets; bf16 outputs stay cached.
// ---------------------------------------------------------------------------
template<int TWO, int RELU_BF, int WF32, int WBF16>
__device__ __forceinline__ void gemm_wide_body(
    const u16* __restrict__ A0, const u16* __restrict__ A1p,
    const u16* __restrict__ B0t, const u16* __restrict__ B1t,
    const float* __restrict__ bias, float* __restrict__ Cf,
    u16* __restrict__ Cb, int M, int bx) {
    __shared__ __align__(16) u16 As[8192];    // [128][64] swizzled (16KB)
    __shared__ __align__(16) u16 Bs[16384];   // [256][64] swizzled (32KB)
    const int tid = threadIdx.x;
    const int wave = tid >> 6;
    const int lane = tid & 63;
    const int bm = bx * 128;
    const int wr = wave >> 2, wc = wave & 3;

    size_t aoff[2];
#pragma unroll
    for (int r = 0; r < 2; ++r) {
        int p = r * 512 + tid;
        int row = p >> 3;
        int s = (p & 7) ^ (row & 7);
        aoff[r] = (size_t)min(bm + row, M - 1) * DD + s * 8;
    }
    size_t boff[4];
#pragma unroll
    for (int r = 0; r < 4; ++r) {
        int p = r * 512 + tid;
        int row = p >> 3;
        int s = (p & 7) ^ (row & 7);
        boff[r] = (size_t)row * DD + s * 8;
    }

    f32x4 acc[4][4] = {};
    const int ra = wr * 64 + (lane & 15);
    const int rb = wc * 64 + (lane & 15);
    const int sF = lane >> 4;

    const int nparts = TWO ? 2 : 1;
    for (int part = 0; part < nparts; ++part) {
        const u16* __restrict__ A  = part ? A1p : A0;
        const u16* __restrict__ Bt = part ? B1t : B0t;
        for (int k0 = 0; k0 < DD; k0 += 64) {
            __syncthreads();
#pragma unroll
            for (int r = 0; r < 2; ++r)
                GLL(A + aoff[r] + k0, As + r * 4096 + wave * 512);
#pragma unroll
            for (int r = 0; r < 4; ++r)
                GLL(Bt + boff[r] + k0, Bs + r * 4096 + wave * 512);
            __syncthreads();

#pragma unroll
            for (int ks = 0; ks < 2; ++ks) {
                bf16x8 af[4], bfr[4];
#pragma unroll
                for (int mi = 0; mi < 4; ++mi) {
                    int row = ra + mi * 16;
                    int sl = (ks * 4 + sF) ^ (row & 7);
                    af[mi] = *(const bf16x8*)(As + row * 64 + sl * 8);
                }
#pragma unroll
                for (int ni = 0; ni < 4; ++ni) {
                    int row = rb + ni * 16;
                    int sl = (ks * 4 + sF) ^ (row & 7);
                    bfr[ni] = *(const bf16x8*)(Bs + row * 64 + sl * 8);
                }
#pragma unroll
                for (int mi = 0; mi < 4; ++mi)
#pragma unroll
                    for (int ni = 0; ni < 4; ++ni)
                        acc[mi][ni] = __builtin_amdgcn_mfma_f32_16x16x32_bf16(
                            af[mi], bfr[ni], acc[mi][ni], 0, 0, 0);
            }
        }
    }

    const int col_l = wc * 64 + (lane & 15);
    const int rbase = bm + wr * 64 + (lane >> 4) * 4;
#pragma unroll
    for (int mi = 0; mi < 4; ++mi) {
#pragma unroll
        for (int r = 0; r < 4; ++r) {
            int row = rbase + mi * 16 + r;
            if (row < M) {
#pragma unroll
                for (int ni = 0; ni < 4; ++ni) {
                    int col = col_l + ni * 16;
                    float v = acc[mi][ni][r] + bias[col];
                    if (WF32)
                        __builtin_nontemporal_store(v, &Cf[(size_t)row * DD + col]);
                    if (WBF16) {
                        float vb = RELU_BF ? fmaxf(v, 0.f) : v;
                        Cb[(size_t)row * DD + col] = f2bf(vb);
                    }
                }
            }
        }
    }
}

template<int TWO, int RELU_BF, int WF32, int WBF16>
__global__ __launch_bounds__(512) void gemm_wide(
    const u16* __restrict__ A0, const u16* __restrict__ A1p,
    const u16* __restrict__ B0t, const u16* __restrict__ B1t,
    const float* __restrict__ bias, float* __restrict__ Cf,
    u16* __restrict__ Cb, int M) {
    gemm_wide_body<TWO, RELU_BF, WF32, WBF16>(A0, A1p, B0t, B1t, bias, Cf, Cb,
                                              M, blockIdx.x);
}

// ---------------------------------------------------------------------------
// emb0_fused (BK=64): A reg-staged from fp32 X; Xq (fp4 or fp8) side-product
// issued during the MFMA phase. emb0 stores nontemporal (final output).
// ---------------------------------------------------------------------------
__global__ __launch_bounds__(512) void emb0_fused(
    const float* __restrict__ X, const u16* __restrict__ Bt,
    const float* __restrict__ bias, float* __restrict__ Cf,
    u32* __restrict__ Xq, int M) {
    __shared__ __align__(16) u16 As[8192];
    __shared__ __align__(16) u16 Bs[16384];
    const int tid = threadIdx.x;
    const int wave = tid >> 6;
    const int lane = tid & 63;
    const int bm = blockIdx.x * 128;
    const int wr = wave >> 2, wc = wave & 3;

    int rowL[2], colS[2];
    bool wq[2];
#pragma unroll
    for (int r = 0; r < 2; ++r) {
        int p = r * 512 + tid;
        int row = p >> 3;
        int s = (p & 7) ^ (row & 7);
        rowL[r] = min(bm + row, M - 1);
        colS[r] = s * 8;
        wq[r] = (bm + row) < M;
    }
    size_t boff[4];
#pragma unroll
    for (int r = 0; r < 4; ++r) {
        int p = r * 512 + tid;
        int row = p >> 3;
        int s = (p & 7) ^ (row & 7);
        boff[r] = (size_t)row * DD + s * 8;
    }

    f32x4 acc[4][4] = {};
    const int ra = wr * 64 + (lane & 15);
    const int rb = wc * 64 + (lane & 15);
    const int sF = lane >> 4;

    for (int k0 = 0; k0 < DD; k0 += 64) {
        float4 x0[2], x1[2];
#pragma unroll
        for (int r = 0; r < 2; ++r) {
            const float* xs = X + (size_t)rowL[r] * DD + k0 + colS[r];
            x0[r] = *(const float4*)xs;
            x1[r] = *(const float4*)(xs + 4);
        }
        __syncthreads();   // previous iteration's LDS reads done
#pragma unroll
        for (int r = 0; r < 4; ++r)
            GLL(Bt + boff[r] + k0, Bs + r * 4096 + wave * 512);
#pragma unroll
        for (int r = 0; r < 2; ++r) {
            bf16x8 av;
            av[0] = (short)f2bf(x0[r].x); av[1] = (short)f2bf(x0[r].y);
            av[2] = (short)f2bf(x0[r].z); av[3] = (short)f2bf(x0[r].w);
            av[4] = (short)f2bf(x1[r].x); av[5] = (short)f2bf(x1[r].y);
            av[6] = (short)f2bf(x1[r].z); av[7] = (short)f2bf(x1[r].w);
            *(bf16x8*)(As + (size_t)(r * 512 + tid) * 8) = av;
        }
        __syncthreads();   // drains GLL (vmcnt) + ds_write (lgkm)

        // Xq side-product during MFMA phase (drains at next iter's barrier)
#pragma unroll
        for (int r = 0; r < 2; ++r) {
            if (wq[r]) {
#ifdef HW_FP4
                u32 q = 0;
                q = __builtin_amdgcn_cvt_scalef32_pk_fp4_f32(q, x0[r].x, x0[r].y, 1.0f, 0);
                q = __builtin_amdgcn_cvt_scalef32_pk_fp4_f32(q, x0[r].z, x0[r].w, 1.0f, 1);
                q = __builtin_amdgcn_cvt_scalef32_pk_fp4_f32(q, x1[r].x, x1[r].y, 1.0f, 2);
                q = __builtin_amdgcn_cvt_scalef32_pk_fp4_f32(q, x1[r].z, x1[r].w, 1.0f, 3);
                Xq[(size_t)rowL[r] * 32 + ((k0 + colS[r]) >> 3)] = q;
#else
                uint2 qq = {pack4_fp8(x0[r]), pack4_fp8(x1[r])};
                *(uint2*)&Xq[(size_t)rowL[r] * 64 + ((k0 + colS[r]) >> 2)] = qq;
#endif
            }
        }

#pragma unroll
        for (int ks = 0; ks < 2; ++ks) {
            bf16x8 af[4], bfr[4];
#pragma unroll
            for (int mi = 0; mi < 4; ++mi) {
                int row = ra + mi * 16;
                int sl = (ks * 4 + sF) ^ (row & 7);
                af[mi] = *(const bf16x8*)(As + row * 64 + sl * 8);
            }
#pragma unroll
            for (int ni = 0; ni < 4; ++ni) {
                int row = rb + ni * 16;
                int sl = (ks * 4 + sF) ^ (row & 7);
                bfr[ni] = *(const bf16x8*)(Bs + row * 64 + sl * 8);
            }
#pragma unroll
            for (int mi = 0; mi < 4; ++mi)
#pragma unroll
                for (int ni = 0; ni < 4; ++ni)
                    acc[mi][ni] = __builtin_amdgcn_mfma_f32_16x16x32_bf16(
                        af[mi], bfr[ni], acc[mi][ni], 0, 0, 0);
        }
    }

    const int col_l = wc * 64 + (lane & 15);
    const int rbase = bm + wr * 64 + (lane >> 4) * 4;
#pragma unroll
    for (int mi = 0; mi < 4; ++mi)
#pragma unroll
        for (int r = 0; r < 4; ++r) {
            int row = rbase + mi * 16 + r;
            if (row < M) {
#pragma unroll
                for (int ni = 0; ni < 4; ++ni) {
                    int col = col_l + ni * 16;
                    __builtin_nontemporal_store(acc[mi][ni][r] + bias[col],
                                                &Cf[(size_t)row * DD + col]);
                }
            }
        }
}

// ---------------------------------------------------------------------------
// emb1 (wide GEMM) + G2 gather in ONE launch — both depend only on H1b.
// ---------------------------------------------------------------------------
__global__ __launch_bounds__(512) void emb1_g2(
    const u16* __restrict__ H1b, const u16* __restrict__ V1t,
    const float* __restrict__ d1c, float* __restrict__ emb1, int C1, int nA,
    const int* __restrict__ d2_bi, const float* __restrict__ d2_bm,
    u16* __restrict__ G2b, int C2) {
    int b = blockIdx.x;
    if (b < nA) {
        gemm_wide_body<0, 0, 1, 0>(H1b, nullptr, V1t, nullptr, d1c, emb1,
                                   nullptr, C1, b);
        return;
    }
    int c = (b - nA) * 8 + (threadIdx.x >> 6);
    if (c >= C2) return;
    int t = threadIdx.x & 63;
    constexpr int K = 8;
    int ids[K];
    float ms[K];
    ushort4 v[K];
#pragma unroll
    for (int k = 0; k < K; ++k) {
        ids[k] = d2_bi[(size_t)c * K + k];
        ms[k] = d2_bm[(size_t)c * K + k];
    }
#pragma unroll
    for (int k = 0; k < K; ++k)
        v[k] = *(const ushort4*)&H1b[(size_t)ids[k] * DD + t * 4];
    float a0 = 0, a1 = 0, a2 = 0, a3 = 0, cnt = 0;
#pragma unroll
    for (int k = 0; k < K; ++k) {
        float m = ms[k];
        cnt += m;
        a0 += m * bf2f(v[k].x); a1 += m * bf2f(v[k].y);
        a2 += m * bf2f(v[k].z); a3 += m * bf2f(v[k].w);
    }
    float inv = (cnt > 0.f) ? 1.f / fmaxf(cnt, 1.f) : 0.f;
    ushort4 o = {f2bf(a0 * inv), f2bf(a1 * inv), f2bf(a2 * inv), f2bf(a3 * inv)};
    *(ushort4*)&G2b[(size_t)c * DD + t * 4] = o;
}

extern "C" void kernel_launch(void* const* d_in, const int* in_sizes, int n_in,
                              void* d_out, int out_size, void* d_ws, size_t ws_size,
                              hipStream_t stream) {
    const float* X     = (const float*)d_in[0];
    const int*   d1_ci = (const int*)d_in[1];
    const int*   d1_bi = (const int*)d_in[2];
    const int*   d2_ci = (const int*)d_in[3];
    const int*   d2_bi = (const int*)d_in[4];
    const float* d1_cm = (const float*)d_in[5];
    const float* d1_bm = (const float*)d_in[6];
    const float* d2_cm = (const float*)d_in[7];
    const float* d2_bm = (const float*)d_in[8];
    const float* W0   = (const float*)d_in[9];
    const float* b0   = (const float*)d_in[10];
    const float* W1a  = (const float*)d_in[11];
    const float* b1a  = (const float*)d_in[12];
    const float* W1b  = (const float*)d_in[13];
    const float* b1b  = (const float*)d_in[14];
    const float* W2a  = (const float*)d_in[15];
    const float* b2a  = (const float*)d_in[16];
    const float* W2b  = (const float*)d_in[17];
    const float* b2b  = (const float*)d_in[18];
    const float* Wout = (const float*)d_in[19];
    const float* bout = (const float*)d_in[20];

    const int N  = in_sizes[0] / DD;   // 100000
    const int C1 = in_sizes[1] / 16;   // 50000
    const int C2 = in_sizes[3] / 32;   // 10000

    float* out  = (float*)d_out;
    float* emb0 = out;
    float* emb1 = out + (size_t)N * DD;
    float* emb2 = out + (size_t)(N + C1) * DD;

    // ---- workspace layout (~122 MB of ~655 MB) ----
    u16* A1b = (u16*)d_ws;                     // [C1,256]
    u16* G1b = A1b + (size_t)C1 * DD;          // [C1,256]
    u16* H1b = G1b + (size_t)C1 * DD;          // [C1,256] relu(h1) bf16
    u16* WT  = H1b + (size_t)C1 * DD;          // 7 x 256x256 bf16 transposed
    float* FW = (float*)(((uintptr_t)(WT + 7 * 65536) + 15) & ~(uintptr_t)15);  // 9 slots
    float* BF = FW + 9 * 65536;                // 7 x 256 fused biases
    u16* A2b = (u16*)(((uintptr_t)(BF + 7 * 256) + 15) & ~(uintptr_t)15);
    u16* G2b = A2b + (size_t)C2 * DD;
    u16* H2b = G2b + (size_t)C2 * DD;
    u32* Xq  = (u32*)(((uintptr_t)(H2b + (size_t)C2 * DD) + 15) & ~(uintptr_t)15);  // fp4/fp8 table

    u16* Wf_t = WT + 0 * 65536;
    u16* U1_t = WT + 1 * 65536;
    u16* V1_t = WT + 2 * 65536;
    u16* U2_t = WT + 3 * 65536;
    u16* V2_t = WT + 4 * 65536;
    u16* P1_t = WT + 5 * 65536;
    u16* P2_t = WT + 6 * 65536;

    dim3 tb(256);
    dim3 tw(512);

    // 1) input-only weight products + biases
    prep1<<<dim3(4, 4, 8), tb, 0, stream>>>(W0, W1a, W1b, W2a, W2b, Wout,
                                            b0, b1a, b1b, b2a, b2b, bout, FW, BF);
    // 2) second-level products P1, P2
    prep2<<<dim3(4, 4, 2), tb, 0, stream>>>(W0, W1b, FW);
    // 3) transpose fused weights -> bf16 [n][k]
    prep3t<<<1792, tb, 0, stream>>>(FW, WT);

    // 4) fused emb0 GEMM (reads fp32 X once, emits emb0 + quantized Xq)
    emb0_fused<<<(N + 127) / 128, tw, 0, stream>>>(
        X, Wf_t, BF + 0, emb0, Xq, N);

    // 5) all X gathers from the quantized table — heavy A2 blocks first,
    //    8 cells per block (half-wave per cell)
    const int n1g = (C1 + 7) / 8;    // 6250
    const int nA2g = (C2 + 7) / 8;   // 1250
    gather3<<<nA2g + 2 * n1g, tb, 0, stream>>>(
        Xq, d1_ci, d1_cm, A1b, d1_bi, d1_bm, G1b, C1, d2_ci, d2_cm, A2b, C2);

    // 6) h1 GEMM (wide): H1b = relu(A1@U1 + G1@P1 + e1) as bf16
    gemm_wide<1, 1, 0, 1><<<(C1 + 127) / 128, tw, 0, stream>>>(
        A1b, G1b, U1_t, P1_t, BF + 5 * 256, nullptr, H1b, C1);

    // 7) emb1 = H1b@V1 + d1c  AND  G2 gather from H1b  (one launch)
    const int nEmb1 = (C1 + 127) / 128;   // 391
    const int nG2   = (C2 + 7) / 8;       // 1250
    emb1_g2<<<nEmb1 + nG2, tw, 0, stream>>>(
        H1b, V1_t, BF + 2 * 256, emb1, C1, nEmb1,
        d2_bi, d2_bm, G2b, C2);

    // 8) h2 GEMM (wide)
    gemm_wide<1, 1, 0, 1><<<(C2 + 127) / 128, tw, 0, stream>>>(
        A2b, G2b, U2_t, P2_t, BF + 6 * 256, nullptr, H2b, C2);

    // 9) emb2 GEMM (wide)
    gemm_wide<0, 0, 1, 0><<<(C2 + 127) / 128, tw, 0, stream>>>(
        H2b, nullptr, V2_t, nullptr, BF + 4 * 256, emb2, nullptr, C2);
}